// Round 1
// baseline (455.703 us; speedup 1.0000x reference)
//
#include <hip/hip_runtime.h>

#define B_ 4
#define C_ 64
#define H_ 128
#define W_ 128
#define O_ 64
#define OCH_ 18          // 2*K*K offset channels
#define PTILE 64         // pixels per block (along wo)

// ---------------- Kernel A: offset = conv3x3(x, offset_w) + offset_b ----------------
// grid: B*18*H*W / 256 threads, lanes along wo (coalesced x, wave-uniform weights)
__global__ __launch_bounds__(256) void offset_conv_kernel(
    const float* __restrict__ x, const float* __restrict__ ow,
    const float* __restrict__ ob, float* __restrict__ off) {
  int idx = blockIdx.x * 256 + threadIdx.x;
  int wo = idx & (W_ - 1);
  int ho = (idx >> 7) & (H_ - 1);
  int t  = idx >> 14;            // b*18 + oc
  int oc = t % OCH_;
  int b  = t / OCH_;
  float acc = ob[oc];
  const float* wbase = ow + (size_t)oc * C_ * 9;
  const float* xb    = x  + (size_t)b * C_ * H_ * W_;
  for (int c = 0; c < C_; ++c) {
    const float* img = xb + (size_t)c * H_ * W_;
    const float* wc  = wbase + c * 9;
    #pragma unroll
    for (int ki = 0; ki < 3; ++ki) {
      int y = ho - 1 + ki;
      if ((unsigned)y >= (unsigned)H_) continue;     // wave-uniform branch
      #pragma unroll
      for (int kj = 0; kj < 3; ++kj) {
        int xq = wo - 1 + kj;
        if ((unsigned)xq >= (unsigned)W_) continue;  // border lanes only
        acc = fmaf(img[y * W_ + xq], wc[ki * 3 + kj], acc);
      }
    }
  }
  off[idx] = acc;
}

// ---------------- Kernel B: deformable sample + einsum + bias ----------------
// block: (b, ho, wo-tile of 64). 256 threads.
// Per tap k: coords -> LDS; s_samp[c][p] cooperative gather; 4o x 4p register FMA.
__global__ __launch_bounds__(256) void deform_main_kernel(
    const float* __restrict__ x, const float* __restrict__ w,
    const float* __restrict__ bias, const float* __restrict__ off,
    float* __restrict__ out) {
  int blk = blockIdx.x;                 // B * H * (W/PTILE) = 1024
  int wt  = blk & (W_ / PTILE - 1);     // 0..1
  int ho  = (blk >> 1) & (H_ - 1);
  int b   = blk >> 8;
  int wo0 = wt * PTILE;
  int tid = threadIdx.x;

  __shared__ float s_w[C_][O_];         // s_w[c][o] = w[o][c][k]   (16 KB)
  __shared__ float s_samp[C_][PTILE];   // sampled[c][p]            (16 KB)
  __shared__ int   s_y0[PTILE], s_x0[PTILE];
  __shared__ float s_wy1[PTILE], s_wx1[PTILE];

  float acc[4][4];                      // [o-sub][p-sub]
  #pragma unroll
  for (int i = 0; i < 4; ++i)
    #pragma unroll
    for (int j = 0; j < 4; ++j) acc[i][j] = 0.f;

  const int og = (tid >> 4) * 4;        // o-block base (16 groups of 4)
  const int pg = (tid & 15) * 4;        // p-block base (16 groups of 4)

  const float* xb = x + (size_t)b * C_ * H_ * W_;

  for (int k = 0; k < 9; ++k) {
    __syncthreads();                    // previous tap's LDS reads done
    // ---- coords for 64 pixels ----
    if (tid < PTILE) {
      int p  = tid;
      int wo = wo0 + p;
      int ki = k / 3, kj = k % 3;
      size_t obase = ((size_t)b * OCH_) * H_ * W_ + (size_t)ho * W_ + wo;
      float dy = off[obase + (size_t)(2 * k)     * H_ * W_];
      float dx = off[obase + (size_t)(2 * k + 1) * H_ * W_];
      float ys = (float)(ho - 1 + ki) + dy;
      float xs = (float)(wo - 1 + kj) + dx;
      float y0f = floorf(ys), x0f = floorf(xs);
      s_y0[p]  = (int)y0f;
      s_x0[p]  = (int)x0f;
      s_wy1[p] = ys - y0f;
      s_wx1[p] = xs - x0f;
    }
    // ---- stage w[:,:,k] transposed: s_w[c][o] ----
    for (int i = tid; i < C_ * O_; i += 256) {
      int c = i >> 6, o = i & 63;
      s_w[c][o] = w[((size_t)o * C_ + c) * 9 + k];
    }
    __syncthreads();
    // ---- bilinear sample: s_samp[c][p] ----
    #pragma unroll
    for (int it = 0; it < (C_ * PTILE) / 256; ++it) {
      int i = tid + it * 256;
      int c = i >> 6, p = i & 63;
      int y0 = s_y0[p], x0 = s_x0[p];
      int y1 = y0 + 1,  x1 = x0 + 1;
      float wy1 = s_wy1[p], wx1 = s_wx1[p];
      float wy0 = 1.f - wy1, wx0 = 1.f - wx1;
      const float* img = xb + (size_t)c * H_ * W_;
      bool vy0 = (unsigned)y0 < (unsigned)H_;
      bool vy1 = (unsigned)y1 < (unsigned)H_;
      bool vx0 = (unsigned)x0 < (unsigned)W_;
      bool vx1 = (unsigned)x1 < (unsigned)W_;
      float v00 = (vy0 && vx0) ? img[y0 * W_ + x0] : 0.f;
      float v01 = (vy0 && vx1) ? img[y0 * W_ + x1] : 0.f;
      float v10 = (vy1 && vx0) ? img[y1 * W_ + x0] : 0.f;
      float v11 = (vy1 && vx1) ? img[y1 * W_ + x1] : 0.f;
      s_samp[c][p] = (v00 * wx0 + v01 * wx1) * wy0 + (v10 * wx0 + v11 * wx1) * wy1;
    }
    __syncthreads();
    // ---- register-blocked contraction: acc[o][p] += w[o,c,k] * samp[c,p] ----
    #pragma unroll 8
    for (int c = 0; c < C_; ++c) {
      float4 wv = *reinterpret_cast<const float4*>(&s_w[c][og]);
      float4 sv = *reinterpret_cast<const float4*>(&s_samp[c][pg]);
      acc[0][0] = fmaf(wv.x, sv.x, acc[0][0]);
      acc[0][1] = fmaf(wv.x, sv.y, acc[0][1]);
      acc[0][2] = fmaf(wv.x, sv.z, acc[0][2]);
      acc[0][3] = fmaf(wv.x, sv.w, acc[0][3]);
      acc[1][0] = fmaf(wv.y, sv.x, acc[1][0]);
      acc[1][1] = fmaf(wv.y, sv.y, acc[1][1]);
      acc[1][2] = fmaf(wv.y, sv.z, acc[1][2]);
      acc[1][3] = fmaf(wv.y, sv.w, acc[1][3]);
      acc[2][0] = fmaf(wv.z, sv.x, acc[2][0]);
      acc[2][1] = fmaf(wv.z, sv.y, acc[2][1]);
      acc[2][2] = fmaf(wv.z, sv.z, acc[2][2]);
      acc[2][3] = fmaf(wv.z, sv.w, acc[2][3]);
      acc[3][0] = fmaf(wv.w, sv.x, acc[3][0]);
      acc[3][1] = fmaf(wv.w, sv.y, acc[3][1]);
      acc[3][2] = fmaf(wv.w, sv.z, acc[3][2]);
      acc[3][3] = fmaf(wv.w, sv.w, acc[3][3]);
    }
  }

  // ---- epilogue: + bias, store float4 per o-row ----
  #pragma unroll
  for (int oi = 0; oi < 4; ++oi) {
    int o = og + oi;
    float bv = bias[o];
    float4 r;
    r.x = acc[oi][0] + bv;
    r.y = acc[oi][1] + bv;
    r.z = acc[oi][2] + bv;
    r.w = acc[oi][3] + bv;
    size_t oidx = (((size_t)b * O_ + o) * H_ + ho) * W_ + wo0 + pg;
    *reinterpret_cast<float4*>(&out[oidx]) = r;
  }
}

extern "C" void kernel_launch(void* const* d_in, const int* in_sizes, int n_in,
                              void* d_out, int out_size, void* d_ws, size_t ws_size,
                              hipStream_t stream) {
  const float* x    = (const float*)d_in[0];
  const float* wt   = (const float*)d_in[1];
  const float* bias = (const float*)d_in[2];
  const float* ow   = (const float*)d_in[3];
  const float* ob   = (const float*)d_in[4];
  float* out = (float*)d_out;
  float* off = (float*)d_ws;   // B*18*H*W floats = 4.7 MB scratch

  int total_off = B_ * OCH_ * H_ * W_;            // 1,179,648
  offset_conv_kernel<<<total_off / 256, 256, 0, stream>>>(x, ow, ob, off);

  int nblk = B_ * H_ * (W_ / PTILE);              // 1024
  deform_main_kernel<<<nblk, 256, 0, stream>>>(x, wt, bias, off, out);
}

// Round 2
// 332.570 us; speedup vs baseline: 1.3702x; 1.3702x over previous
//
#include <hip/hip_runtime.h>

#define B_ 4
#define C_ 64
#define H_ 128
#define W_ 128
#define O_ 64
#define OCH_ 18          // 2*K*K offset channels
#define PTILE 64         // pixels per block (along wo) for kernel B

// ---------------- Kernel A v2: offset = conv3x3(x, offset_w) + offset_b ----------------
// block = (b, ho): 512 blocks, 256 threads = 4 waves.
// lanes = 128 pixels (2 waves), x2 waves splitting 18 oc into two 9-halves.
// x staged in LDS 8 channels at a time; weights via wave-uniform s_load (SGPR fma operand).
__global__ __launch_bounds__(256) void offset_conv_v2(
    const float* __restrict__ x, const float* __restrict__ ow,
    const float* __restrict__ ob, float* __restrict__ off) {
  const int ho = blockIdx.x & (H_ - 1);
  const int b  = blockIdx.x >> 7;
  const int tid = threadIdx.x;
  const int p   = tid & (W_ - 1);                 // pixel 0..127
  // wave-uniform oc-half base; readfirstlane forces SGPR so weight loads scalarize
  const int ocb = __builtin_amdgcn_readfirstlane((tid >> 7) * 9);

  __shared__ float s_x[8][3][W_ + 2];             // 12.5 KB, cols -1..128

  const float* xb = x + (size_t)b * C_ * H_ * W_;

  float acc[9];
  #pragma unroll
  for (int j = 0; j < 9; ++j) acc[j] = 0.f;

  for (int chunk = 0; chunk < C_ / 8; ++chunk) {
    __syncthreads();
    // ---- stage 8 channels x 3 rows x 130 cols (zero-padded) ----
    for (int i = tid; i < 8 * 3 * (W_ + 2); i += 256) {
      int c   = i / (3 * (W_ + 2));
      int rem = i - c * 3 * (W_ + 2);
      int r   = rem / (W_ + 2);
      int j   = rem - r * (W_ + 2);
      int row = ho - 1 + r;
      int col = j - 1;
      float v = 0.f;
      if ((unsigned)row < (unsigned)H_ && (unsigned)col < (unsigned)W_)
        v = xb[((size_t)(chunk * 8 + c) * H_ + row) * W_ + col];
      s_x[c][r][j] = v;
    }
    __syncthreads();
    // ---- accumulate 8 channels ----
    #pragma unroll
    for (int cc = 0; cc < 8; ++cc) {
      const int cg = chunk * 8 + cc;
      float xv[9];
      #pragma unroll
      for (int r = 0; r < 3; ++r)
        #pragma unroll
        for (int kj = 0; kj < 3; ++kj)
          xv[r * 3 + kj] = s_x[cc][r][p + kj];    // col p+kj-1 (global), stride-1
      #pragma unroll
      for (int j = 0; j < 9; ++j) {
        const float* wr = ow + ((size_t)(ocb + j) * C_ + cg) * 9;  // uniform -> s_load
        #pragma unroll
        for (int t = 0; t < 9; ++t)
          acc[j] = fmaf(wr[t], xv[t], acc[j]);
      }
    }
  }

  #pragma unroll
  for (int j = 0; j < 9; ++j) {
    int oc = ocb + j;
    off[(((size_t)b * OCH_ + oc) * H_ + ho) * W_ + p] = acc[j] + ob[oc];
  }
}

// ---------------- Kernel B: deformable sample + einsum + bias (unchanged) ----------------
__global__ __launch_bounds__(256) void deform_main_kernel(
    const float* __restrict__ x, const float* __restrict__ w,
    const float* __restrict__ bias, const float* __restrict__ off,
    float* __restrict__ out) {
  int blk = blockIdx.x;                 // B * H * (W/PTILE) = 1024
  int wt  = blk & (W_ / PTILE - 1);     // 0..1
  int ho  = (blk >> 1) & (H_ - 1);
  int b   = blk >> 8;
  int wo0 = wt * PTILE;
  int tid = threadIdx.x;

  __shared__ float s_w[C_][O_];         // s_w[c][o] = w[o][c][k]   (16 KB)
  __shared__ float s_samp[C_][PTILE];   // sampled[c][p]            (16 KB)
  __shared__ int   s_y0[PTILE], s_x0[PTILE];
  __shared__ float s_wy1[PTILE], s_wx1[PTILE];

  float acc[4][4];                      // [o-sub][p-sub]
  #pragma unroll
  for (int i = 0; i < 4; ++i)
    #pragma unroll
    for (int j = 0; j < 4; ++j) acc[i][j] = 0.f;

  const int og = (tid >> 4) * 4;        // o-block base (16 groups of 4)
  const int pg = (tid & 15) * 4;        // p-block base (16 groups of 4)

  const float* xb = x + (size_t)b * C_ * H_ * W_;

  for (int k = 0; k < 9; ++k) {
    __syncthreads();                    // previous tap's LDS reads done
    // ---- coords for 64 pixels ----
    if (tid < PTILE) {
      int p  = tid;
      int wo = wo0 + p;
      int ki = k / 3, kj = k % 3;
      size_t obase = ((size_t)b * OCH_) * H_ * W_ + (size_t)ho * W_ + wo;
      float dy = off[obase + (size_t)(2 * k)     * H_ * W_];
      float dx = off[obase + (size_t)(2 * k + 1) * H_ * W_];
      float ys = (float)(ho - 1 + ki) + dy;
      float xs = (float)(wo - 1 + kj) + dx;
      float y0f = floorf(ys), x0f = floorf(xs);
      s_y0[p]  = (int)y0f;
      s_x0[p]  = (int)x0f;
      s_wy1[p] = ys - y0f;
      s_wx1[p] = xs - x0f;
    }
    // ---- stage w[:,:,k] transposed: s_w[c][o] ----
    for (int i = tid; i < C_ * O_; i += 256) {
      int c = i >> 6, o = i & 63;
      s_w[c][o] = w[((size_t)o * C_ + c) * 9 + k];
    }
    __syncthreads();
    // ---- bilinear sample: s_samp[c][p] ----
    #pragma unroll
    for (int it = 0; it < (C_ * PTILE) / 256; ++it) {
      int i = tid + it * 256;
      int c = i >> 6, p = i & 63;
      int y0 = s_y0[p], x0 = s_x0[p];
      int y1 = y0 + 1,  x1 = x0 + 1;
      float wy1 = s_wy1[p], wx1 = s_wx1[p];
      float wy0 = 1.f - wy1, wx0 = 1.f - wx1;
      const float* img = xb + (size_t)c * H_ * W_;
      bool vy0 = (unsigned)y0 < (unsigned)H_;
      bool vy1 = (unsigned)y1 < (unsigned)H_;
      bool vx0 = (unsigned)x0 < (unsigned)W_;
      bool vx1 = (unsigned)x1 < (unsigned)W_;
      float v00 = (vy0 && vx0) ? img[y0 * W_ + x0] : 0.f;
      float v01 = (vy0 && vx1) ? img[y0 * W_ + x1] : 0.f;
      float v10 = (vy1 && vx0) ? img[y1 * W_ + x0] : 0.f;
      float v11 = (vy1 && vx1) ? img[y1 * W_ + x1] : 0.f;
      s_samp[c][p] = (v00 * wx0 + v01 * wx1) * wy0 + (v10 * wx0 + v11 * wx1) * wy1;
    }
    __syncthreads();
    // ---- register-blocked contraction: acc[o][p] += w[o,c,k] * samp[c,p] ----
    #pragma unroll 8
    for (int c = 0; c < C_; ++c) {
      float4 wv = *reinterpret_cast<const float4*>(&s_w[c][og]);
      float4 sv = *reinterpret_cast<const float4*>(&s_samp[c][pg]);
      acc[0][0] = fmaf(wv.x, sv.x, acc[0][0]);
      acc[0][1] = fmaf(wv.x, sv.y, acc[0][1]);
      acc[0][2] = fmaf(wv.x, sv.z, acc[0][2]);
      acc[0][3] = fmaf(wv.x, sv.w, acc[0][3]);
      acc[1][0] = fmaf(wv.y, sv.x, acc[1][0]);
      acc[1][1] = fmaf(wv.y, sv.y, acc[1][1]);
      acc[1][2] = fmaf(wv.y, sv.z, acc[1][2]);
      acc[1][3] = fmaf(wv.y, sv.w, acc[1][3]);
      acc[2][0] = fmaf(wv.z, sv.x, acc[2][0]);
      acc[2][1] = fmaf(wv.z, sv.y, acc[2][1]);
      acc[2][2] = fmaf(wv.z, sv.z, acc[2][2]);
      acc[2][3] = fmaf(wv.z, sv.w, acc[2][3]);
      acc[3][0] = fmaf(wv.w, sv.x, acc[3][0]);
      acc[3][1] = fmaf(wv.w, sv.y, acc[3][1]);
      acc[3][2] = fmaf(wv.w, sv.z, acc[3][2]);
      acc[3][3] = fmaf(wv.w, sv.w, acc[3][3]);
    }
  }

  // ---- epilogue: + bias, store float4 per o-row ----
  #pragma unroll
  for (int oi = 0; oi < 4; ++oi) {
    int o = og + oi;
    float bv = bias[o];
    float4 r;
    r.x = acc[oi][0] + bv;
    r.y = acc[oi][1] + bv;
    r.z = acc[oi][2] + bv;
    r.w = acc[oi][3] + bv;
    size_t oidx = (((size_t)b * O_ + o) * H_ + ho) * W_ + wo0 + pg;
    *reinterpret_cast<float4*>(&out[oidx]) = r;
  }
}

extern "C" void kernel_launch(void* const* d_in, const int* in_sizes, int n_in,
                              void* d_out, int out_size, void* d_ws, size_t ws_size,
                              hipStream_t stream) {
  const float* x    = (const float*)d_in[0];
  const float* wt   = (const float*)d_in[1];
  const float* bias = (const float*)d_in[2];
  const float* ow   = (const float*)d_in[3];
  const float* ob   = (const float*)d_in[4];
  float* out = (float*)d_out;
  float* off = (float*)d_ws;   // B*18*H*W floats = 4.7 MB scratch

  offset_conv_v2<<<B_ * H_, 256, 0, stream>>>(x, ow, ob, off);

  int nblk = B_ * H_ * (W_ / PTILE);              // 1024
  deform_main_kernel<<<nblk, 256, 0, stream>>>(x, wt, bias, off, out);
}

// Round 3
// 126.403 us; speedup vs baseline: 3.6052x; 2.6310x over previous
//
#include <hip/hip_runtime.h>

#define B_ 4
#define C_ 64
#define H_ 128
#define W_ 128
#define HW_ (H_ * W_)
#define OCH_ 18

typedef __attribute__((ext_vector_type(8))) short short8;
typedef __attribute__((ext_vector_type(16))) float f32x16;

// ws layout (bytes):
//   [0, 73728)            w2b: main weights packed in A-frag order (bf16)
//   [73728, 110592)       w2a: offset-conv weights packed in A-frag order (bf16)
//   [131072, 131072+2.36M) off: predicted offsets, bf16, [b][18][H][W]
#define W2B_ELEMS (9 * 2 * 4 * 64 * 8)   // 36864
#define W2A_ELEMS (36 * 64 * 8)          // 18432
#define OFF_BYTE_OFS 131072

__device__ __forceinline__ unsigned short f2bf(float f) {
  union { float f; unsigned u; } v; v.f = f;
  unsigned r = v.u + 0x7FFFu + ((v.u >> 16) & 1u);   // RNE
  return (unsigned short)(r >> 16);
}
__device__ __forceinline__ float bf2f(unsigned short h) {
  union { unsigned u; float f; } v; v.u = ((unsigned)h) << 16;
  return v.f;
}

// ---------------- pack kernel: weights -> A-fragment order, bf16 ----------------
// w2b[t][mq][s][lane][i] = w[o=mq*32+(lane&31)][c=16s+(lane>>5)*8+i][t]
// w2a[s][lane][i]        = offw[oc=lane&31][c=kg&63][t=kg>>6], kg=16s+(lane>>5)*8+i  (0 for oc>=18)
__global__ __launch_bounds__(256) void pack_w(
    const float* __restrict__ wmain, const float* __restrict__ offw,
    unsigned short* __restrict__ ws) {
  int idx = blockIdx.x * 256 + threadIdx.x;
  if (idx < W2B_ELEMS) {
    int i = idx & 7, lane = (idx >> 3) & 63, s = (idx >> 9) & 3;
    int mq = (idx >> 11) & 1, t = idx >> 12;
    int o = mq * 32 + (lane & 31);
    int c = 16 * s + (lane >> 5) * 8 + i;
    ws[idx] = f2bf(wmain[(o * 64 + c) * 9 + t]);
  } else if (idx < W2B_ELEMS + W2A_ELEMS) {
    int j = idx - W2B_ELEMS;
    int i = j & 7, lane = (j >> 3) & 63, s = j >> 9;   // s 0..35
    int kg = 16 * s + (lane >> 5) * 8 + i;
    int t = kg >> 6, c = kg & 63, oc = lane & 31;
    ws[idx] = (oc < OCH_) ? f2bf(offw[(oc * 64 + c) * 9 + t]) : (unsigned short)0;
  }
}

// ---------------- Kernel A: offset conv via MFMA ----------------
// block=(b,ho), 4 waves; wave = 32-px strip. M=32 (oc, 18 valid), K=576 (k=t*64+c), N=32.
// x staged once: sx[r][col][cblk^ (col&7)][c&7] bf16, 3x130x64.
__global__ __launch_bounds__(256) void offset_conv_mfma(
    const float* __restrict__ x, const float* __restrict__ ob,
    const unsigned short* __restrict__ w2a, unsigned short* __restrict__ offout) {
  const int ho = blockIdx.x & (H_ - 1);
  const int b  = blockIdx.x >> 7;
  const int tid = threadIdx.x;
  const int lane = tid & 63;
  const int wv = tid >> 6;

  __shared__ __align__(16) unsigned short sx[3 * 130 * 64];   // 48.75 KB

  const float* xb = x + (size_t)b * C_ * HW_;

  // ---- stage 3 rows x 130 cols x 64 ch, bf16-pair writes, swizzled ----
  for (int i = tid; i < 96 * 130; i += 256) {
    int col = i % 130;
    int c2  = i / 130;            // 0..95
    int r   = c2 >> 5;            // 0..2
    int c   = (c2 & 31) * 2;      // even channel
    int row = ho - 1 + r, gcol = col - 1;
    float v0 = 0.f, v1 = 0.f;
    if ((unsigned)row < (unsigned)H_ && (unsigned)gcol < (unsigned)W_) {
      v0 = xb[(size_t)c * HW_ + row * W_ + gcol];
      v1 = xb[(size_t)(c + 1) * HW_ + row * W_ + gcol];
    }
    unsigned pk = (unsigned)f2bf(v0) | ((unsigned)f2bf(v1) << 16);
    int cblk = (c >> 3) ^ (col & 7);
    int h = ((r * 130 + col) * 8 + cblk) * 8 + (c & 7);
    *(unsigned*)&sx[h] = pk;
  }
  __syncthreads();

  const int px  = wv * 32 + (lane & 31);
  const int cbh = lane >> 5;          // k-half

  f32x16 acc;
  #pragma unroll
  for (int r = 0; r < 16; ++r) acc[r] = 0.f;

  for (int s = 0; s < 36; ++s) {
    int t  = s >> 2;                  // tap
    int ki = t / 3, kj = t - 3 * ki;
    int j  = px + kj;                 // LDS col (global col px-1+kj, +1 pad)
    int cblk = (s & 3) * 2 + cbh;
    const short8 bfr = *(const short8*)&sx[((ki * 130 + j) * 8 + (cblk ^ (j & 7))) * 8];
    const short8 afr = *(const short8*)&w2a[(s * 64 + lane) * 8];
    acc = __builtin_amdgcn_mfma_f32_32x32x16_bf16(afr, bfr, acc, 0, 0, 0);
  }

  // epilogue: oc = (reg&3)+8*(reg>>2)+4*(lane>>5); store bf16 offsets
  #pragma unroll
  for (int reg = 0; reg < 16; ++reg) {
    int oc = (reg & 3) + 8 * (reg >> 2) + 4 * (lane >> 5);
    if (oc < OCH_) {
      float v = acc[reg] + ob[oc];
      offout[((b * OCH_ + oc) * H_ + ho) * W_ + px] = f2bf(v);
    }
  }
}

// ---------------- Kernel B: deformable sample + MFMA einsum ----------------
// block=(b,ho), 4 waves; wave: M=64 (2 acc), N=32 px strip, K=576 (9 taps x 4 steps).
// B-frag gathered directly into registers (no LDS): per-lane bilinear weights folded w/ validity.
__global__ __launch_bounds__(256) void deform_mfma(
    const float* __restrict__ x, const float* __restrict__ bias,
    const unsigned short* __restrict__ w2b, const unsigned short* __restrict__ offb,
    float* __restrict__ out) {
  const int ho = blockIdx.x & (H_ - 1);
  const int b  = blockIdx.x >> 7;
  const int lane = threadIdx.x & 63;
  const int wv   = threadIdx.x >> 6;
  const int px   = wv * 32 + (lane & 31);
  const int cb   = (lane >> 5) * 8;      // k-half channel base

  const float* xb = x + (size_t)b * C_ * HW_;

  f32x16 acc0, acc1;
  #pragma unroll
  for (int r = 0; r < 16; ++r) { acc0[r] = 0.f; acc1[r] = 0.f; }

  for (int t = 0; t < 9; ++t) {
    const int ki = t / 3, kj = t - 3 * ki;
    // offsets (bf16 -> f32)
    float dy = bf2f(offb[((b * OCH_ + 2 * t)     * H_ + ho) * W_ + px]);
    float dx = bf2f(offb[((b * OCH_ + 2 * t + 1) * H_ + ho) * W_ + px]);
    float ys = (float)(ho - 1 + ki) + dy;
    float xs = (float)(px - 1 + kj) + dx;
    float y0f = floorf(ys), x0f = floorf(xs);
    int y0 = (int)y0f, x0 = (int)x0f;
    int y1 = y0 + 1,   x1 = x0 + 1;
    float wy1 = ys - y0f, wx1 = xs - x0f;
    float wy0 = 1.f - wy1, wx0 = 1.f - wx1;
    bool vy0 = (unsigned)y0 < (unsigned)H_, vy1 = (unsigned)y1 < (unsigned)H_;
    bool vx0 = (unsigned)x0 < (unsigned)W_, vx1 = (unsigned)x1 < (unsigned)W_;
    int yc0 = min(max(y0, 0), H_ - 1), yc1 = min(max(y1, 0), H_ - 1);
    int xc0 = min(max(x0, 0), W_ - 1), xc1 = min(max(x1, 0), W_ - 1);
    const int o00 = yc0 * W_ + xc0, o01 = yc0 * W_ + xc1;
    const int o10 = yc1 * W_ + xc0, o11 = yc1 * W_ + xc1;
    const float g00 = (vy0 && vx0) ? wy0 * wx0 : 0.f;
    const float g01 = (vy0 && vx1) ? wy0 * wx1 : 0.f;
    const float g10 = (vy1 && vx0) ? wy1 * wx0 : 0.f;
    const float g11 = (vy1 && vx1) ? wy1 * wx1 : 0.f;

    // A-fragments for this tap (coalesced 16B/lane, L2-resident)
    const short8* wp = (const short8*)(w2b + (size_t)t * 2 * 4 * 64 * 8);
    short8 a0[4], a1[4];
    #pragma unroll
    for (int s = 0; s < 4; ++s) {
      a0[s] = wp[s * 64 + lane];
      a1[s] = wp[(4 + s) * 64 + lane];
    }

    #pragma unroll
    for (int s = 0; s < 4; ++s) {
      const int cidx = (cb + 16 * s) * HW_;
      short8 bf;
      #pragma unroll
      for (int i = 0; i < 8; ++i) {
        const int bi = cidx + i * HW_;       // 32-bit index -> SGPR-base+voffset loads
        float v = g00 * xb[bi + o00] + g01 * xb[bi + o01]
                + g10 * xb[bi + o10] + g11 * xb[bi + o11];
        bf[i] = (short)f2bf(v);
      }
      acc0 = __builtin_amdgcn_mfma_f32_32x32x16_bf16(a0[s], bf, acc0, 0, 0, 0);
      acc1 = __builtin_amdgcn_mfma_f32_32x32x16_bf16(a1[s], bf, acc1, 0, 0, 0);
    }
  }

  // epilogue: o = mq*32 + (reg&3)+8*(reg>>2)+4*(lane>>5); col = px
  #pragma unroll
  for (int reg = 0; reg < 16; ++reg) {
    int row = (reg & 3) + 8 * (reg >> 2) + 4 * (lane >> 5);
    out[((b * 64 + row)      * H_ + ho) * W_ + px] = acc0[reg] + bias[row];
    out[((b * 64 + 32 + row) * H_ + ho) * W_ + px] = acc1[reg] + bias[32 + row];
  }
}

extern "C" void kernel_launch(void* const* d_in, const int* in_sizes, int n_in,
                              void* d_out, int out_size, void* d_ws, size_t ws_size,
                              hipStream_t stream) {
  const float* x    = (const float*)d_in[0];
  const float* wt   = (const float*)d_in[1];
  const float* bias = (const float*)d_in[2];
  const float* ow   = (const float*)d_in[3];
  const float* ob   = (const float*)d_in[4];
  float* out = (float*)d_out;

  unsigned short* ws_u  = (unsigned short*)d_ws;
  unsigned short* w2b   = ws_u;
  unsigned short* w2a   = ws_u + W2B_ELEMS;
  unsigned short* offbf = (unsigned short*)((char*)d_ws + OFF_BYTE_OFS);

  int pack_total = W2B_ELEMS + W2A_ELEMS;               // 55296
  pack_w<<<(pack_total + 255) / 256, 256, 0, stream>>>(wt, ow, ws_u);

  offset_conv_mfma<<<B_ * H_, 256, 0, stream>>>(x, ob, w2a, offbf);

  deform_mfma<<<B_ * H_, 256, 0, stream>>>(x, bias, w2b, offbf, out);
}

// Round 4
// 69.203 us; speedup vs baseline: 6.5850x; 1.8266x over previous
//
#include <hip/hip_runtime.h>

#define B_ 4
#define C_ 64
#define H_ 128
#define W_ 128
#define HW_ (H_ * W_)
#define OCH_ 18

typedef __attribute__((ext_vector_type(8))) short short8;
typedef __attribute__((ext_vector_type(16))) float f32x16;

// ws layout (bytes):
//   [0, 73728)                      w2b: main weights, A-frag order (bf16)
//   [73728, 110592)                 w2a: offset-conv weights, A-frag order (bf16)
//   [131072, 131072+2359296)        off: predicted offsets, bf16, [b][18][H][W]
//   [2490368, 2490368+8388608)      xh : x in NHWC bf16, [b][h][w][c]
#define W2B_ELEMS (9 * 2 * 4 * 64 * 8)   // 36864
#define W2A_ELEMS (36 * 64 * 8)          // 18432
#define OFF_BYTE_OFS 131072
#define XH_BYTE_OFS  2490368
#define WS_NEED (XH_BYTE_OFS + (size_t)B_ * H_ * W_ * C_ * 2)

__device__ __forceinline__ unsigned short f2bf(float f) {
  union { float f; unsigned u; } v; v.f = f;
  unsigned r = v.u + 0x7FFFu + ((v.u >> 16) & 1u);   // RNE
  return (unsigned short)(r >> 16);
}
__device__ __forceinline__ float bf2f(unsigned short h) {
  union { unsigned u; float f; } v; v.u = ((unsigned)h) << 16;
  return v.f;
}
// bijective XCD swizzle for 512-block grids (512 % 8 == 0)
__device__ __forceinline__ int swz512(int x) { return (x & 7) * 64 + (x >> 3); }

// ---------------- pack kernel: weights -> A-fragment order, bf16 ----------------
__global__ __launch_bounds__(256) void pack_w(
    const float* __restrict__ wmain, const float* __restrict__ offw,
    unsigned short* __restrict__ ws) {
  int idx = blockIdx.x * 256 + threadIdx.x;
  if (idx < W2B_ELEMS) {
    int i = idx & 7, lane = (idx >> 3) & 63, s = (idx >> 9) & 3;
    int mq = (idx >> 11) & 1, t = idx >> 12;
    int o = mq * 32 + (lane & 31);
    int c = 16 * s + (lane >> 5) * 8 + i;
    ws[idx] = f2bf(wmain[(o * 64 + c) * 9 + t]);
  } else if (idx < W2B_ELEMS + W2A_ELEMS) {
    int j = idx - W2B_ELEMS;
    int i = j & 7, lane = (j >> 3) & 63, s = j >> 9;   // s 0..35
    int kg = 16 * s + (lane >> 5) * 8 + i;
    int t = kg >> 6, c = kg & 63, oc = lane & 31;
    ws[idx] = (oc < OCH_) ? f2bf(offw[(oc * 64 + c) * 9 + t]) : (unsigned short)0;
  }
}

// ---------------- NHWC repack: x[b][c][h][w] f32 -> xh[b][h][w][c] bf16 ----------------
__global__ __launch_bounds__(256) void nhwc_pack(
    const float* __restrict__ x, unsigned short* __restrict__ xh) {
  __shared__ float s[W_ * 65];                // [w][c], pad 65 (conflict-free both phases)
  const int h = blockIdx.x & (H_ - 1);
  const int b = blockIdx.x >> 7;
  const int tid = threadIdx.x;
  const float* xb = x + ((size_t)b * C_ * H_ + h) * W_;
  for (int i = tid; i < C_ * W_; i += 256) {
    int c = i >> 7, w = i & (W_ - 1);
    s[w * 65 + c] = xb[(size_t)c * HW_ + w];
  }
  __syncthreads();
  unsigned short* dst = xh + ((size_t)(b * H_ + h) * W_) * C_;
  for (int i = tid; i < W_ * 8; i += 256) {
    int w = i >> 3, g = i & 7;
    short8 v;
    #pragma unroll
    for (int j = 0; j < 8; ++j) v[j] = (short)f2bf(s[w * 65 + g * 8 + j]);
    *(short8*)&dst[w * C_ + g * 8] = v;
  }
}

// ---------------- Kernel A v3: offset conv via MFMA, NHWC direct loads ----------------
__global__ __launch_bounds__(256) void offset_conv_nhwc(
    const unsigned short* __restrict__ xh, const float* __restrict__ ob,
    const unsigned short* __restrict__ w2a, unsigned short* __restrict__ offout) {
  const int blk = swz512(blockIdx.x);
  const int ho = blk & (H_ - 1);
  const int b  = blk >> 7;
  const int lane = threadIdx.x & 63;
  const int wv   = threadIdx.x >> 6;
  const int px   = wv * 32 + (lane & 31);
  const int ch   = (lane >> 5) * 8;

  f32x16 acc;
  #pragma unroll
  for (int r = 0; r < 16; ++r) acc[r] = 0.f;

  #pragma unroll
  for (int s = 0; s < 36; ++s) {
    const int t  = s >> 2;
    const int ki = t / 3, kj = t - 3 * ki;
    const int row = ho - 1 + ki;
    const int col = px - 1 + kj;
    short8 bfr = {0, 0, 0, 0, 0, 0, 0, 0};
    if ((unsigned)row < (unsigned)H_ && (unsigned)col < (unsigned)W_)
      bfr = *(const short8*)&xh[(((b * H_ + row) * W_ + col) * C_) + (s & 3) * 16 + ch];
    const short8 afr = *(const short8*)&w2a[(s * 64 + lane) * 8];
    acc = __builtin_amdgcn_mfma_f32_32x32x16_bf16(afr, bfr, acc, 0, 0, 0);
  }

  #pragma unroll
  for (int reg = 0; reg < 16; ++reg) {
    int oc = (reg & 3) + 8 * (reg >> 2) + 4 * (lane >> 5);
    if (oc < OCH_) {
      float v = acc[reg] + ob[oc];
      offout[((b * OCH_ + oc) * H_ + ho) * W_ + px] = f2bf(v);
    }
  }
}

// ---------------- Kernel B v3: deformable sample + MFMA, NHWC 16B gathers ----------------
__global__ __launch_bounds__(256) void deform_nhwc(
    const unsigned short* __restrict__ xh, const float* __restrict__ bias,
    const unsigned short* __restrict__ w2b, const unsigned short* __restrict__ offb,
    float* __restrict__ out) {
  const int blk = swz512(blockIdx.x);
  const int ho = blk & (H_ - 1);
  const int b  = blk >> 7;
  const int lane = threadIdx.x & 63;
  const int wv   = threadIdx.x >> 6;
  const int px   = wv * 32 + (lane & 31);
  const int cb   = (lane >> 5) * 8;

  f32x16 acc0, acc1;
  #pragma unroll
  for (int r = 0; r < 16; ++r) { acc0[r] = 0.f; acc1[r] = 0.f; }

  for (int t = 0; t < 9; ++t) {
    const int ki = t / 3, kj = t - 3 * ki;
    float dy = bf2f(offb[((b * OCH_ + 2 * t)     * H_ + ho) * W_ + px]);
    float dx = bf2f(offb[((b * OCH_ + 2 * t + 1) * H_ + ho) * W_ + px]);
    float ys = (float)(ho - 1 + ki) + dy;
    float xs = (float)(px - 1 + kj) + dx;
    float y0f = floorf(ys), x0f = floorf(xs);
    int y0 = (int)y0f, x0 = (int)x0f;
    int y1 = y0 + 1,   x1 = x0 + 1;
    float wy1 = ys - y0f, wx1 = xs - x0f;
    float wy0 = 1.f - wy1, wx0 = 1.f - wx1;
    bool vy0 = (unsigned)y0 < (unsigned)H_, vy1 = (unsigned)y1 < (unsigned)H_;
    bool vx0 = (unsigned)x0 < (unsigned)W_, vx1 = (unsigned)x1 < (unsigned)W_;
    int yc0 = min(max(y0, 0), H_ - 1), yc1 = min(max(y1, 0), H_ - 1);
    int xc0 = min(max(x0, 0), W_ - 1), xc1 = min(max(x1, 0), W_ - 1);
    const float g00 = (vy0 && vx0) ? wy0 * wx0 : 0.f;
    const float g01 = (vy0 && vx1) ? wy0 * wx1 : 0.f;
    const float g10 = (vy1 && vx0) ? wy1 * wx0 : 0.f;
    const float g11 = (vy1 && vx1) ? wy1 * wx1 : 0.f;
    // NHWC pixel bases (one 128B line each)
    const int p00 = ((b * H_ + yc0) * W_ + xc0) * C_ + cb;
    const int p01 = ((b * H_ + yc0) * W_ + xc1) * C_ + cb;
    const int p10 = ((b * H_ + yc1) * W_ + xc0) * C_ + cb;
    const int p11 = ((b * H_ + yc1) * W_ + xc1) * C_ + cb;

    // ---- issue all VMEM for this tap up front: 16 corner 16B loads + 8 A-frags ----
    short8 cr[4][4];
    #pragma unroll
    for (int s = 0; s < 4; ++s) {
      cr[s][0] = *(const short8*)&xh[p00 + 16 * s];
      cr[s][1] = *(const short8*)&xh[p01 + 16 * s];
      cr[s][2] = *(const short8*)&xh[p10 + 16 * s];
      cr[s][3] = *(const short8*)&xh[p11 + 16 * s];
    }
    const short8* wp = (const short8*)(w2b + (size_t)t * 2 * 4 * 64 * 8);
    short8 a0[4], a1[4];
    #pragma unroll
    for (int s = 0; s < 4; ++s) {
      a0[s] = wp[s * 64 + lane];
      a1[s] = wp[(4 + s) * 64 + lane];
    }

    // ---- blend + MFMA ----
    #pragma unroll
    for (int s = 0; s < 4; ++s) {
      short8 bf;
      #pragma unroll
      for (int i = 0; i < 8; ++i) {
        float v = g00 * bf2f((unsigned short)cr[s][0][i])
                + g01 * bf2f((unsigned short)cr[s][1][i])
                + g10 * bf2f((unsigned short)cr[s][2][i])
                + g11 * bf2f((unsigned short)cr[s][3][i]);
        bf[i] = (short)f2bf(v);
      }
      acc0 = __builtin_amdgcn_mfma_f32_32x32x16_bf16(a0[s], bf, acc0, 0, 0, 0);
      acc1 = __builtin_amdgcn_mfma_f32_32x32x16_bf16(a1[s], bf, acc1, 0, 0, 0);
    }
  }

  #pragma unroll
  for (int reg = 0; reg < 16; ++reg) {
    int row = (reg & 3) + 8 * (reg >> 2) + 4 * (lane >> 5);
    out[((b * 64 + row)      * H_ + ho) * W_ + px] = acc0[reg] + bias[row];
    out[((b * 64 + 32 + row) * H_ + ho) * W_ + px] = acc1[reg] + bias[32 + row];
  }
}

// ================= fallback path (round-3, used only if ws too small) =================
__global__ __launch_bounds__(256) void offset_conv_mfma(
    const float* __restrict__ x, const float* __restrict__ ob,
    const unsigned short* __restrict__ w2a, unsigned short* __restrict__ offout) {
  const int ho = blockIdx.x & (H_ - 1);
  const int b  = blockIdx.x >> 7;
  const int tid = threadIdx.x;
  const int lane = tid & 63;
  const int wv = tid >> 6;
  __shared__ __align__(16) unsigned short sx[3 * 130 * 64];
  const float* xb = x + (size_t)b * C_ * HW_;
  for (int i = tid; i < 96 * 130; i += 256) {
    int col = i % 130;
    int c2  = i / 130;
    int r   = c2 >> 5;
    int c   = (c2 & 31) * 2;
    int row = ho - 1 + r, gcol = col - 1;
    float v0 = 0.f, v1 = 0.f;
    if ((unsigned)row < (unsigned)H_ && (unsigned)gcol < (unsigned)W_) {
      v0 = xb[(size_t)c * HW_ + row * W_ + gcol];
      v1 = xb[(size_t)(c + 1) * HW_ + row * W_ + gcol];
    }
    unsigned pk = (unsigned)f2bf(v0) | ((unsigned)f2bf(v1) << 16);
    int cblk = (c >> 3) ^ (col & 7);
    int h = ((r * 130 + col) * 8 + cblk) * 8 + (c & 7);
    *(unsigned*)&sx[h] = pk;
  }
  __syncthreads();
  const int px  = wv * 32 + (lane & 31);
  const int cbh = lane >> 5;
  f32x16 acc;
  #pragma unroll
  for (int r = 0; r < 16; ++r) acc[r] = 0.f;
  for (int s = 0; s < 36; ++s) {
    int t  = s >> 2;
    int ki = t / 3, kj = t - 3 * ki;
    int j  = px + kj;
    int cblk = (s & 3) * 2 + cbh;
    const short8 bfr = *(const short8*)&sx[((ki * 130 + j) * 8 + (cblk ^ (j & 7))) * 8];
    const short8 afr = *(const short8*)&w2a[(s * 64 + lane) * 8];
    acc = __builtin_amdgcn_mfma_f32_32x32x16_bf16(afr, bfr, acc, 0, 0, 0);
  }
  #pragma unroll
  for (int reg = 0; reg < 16; ++reg) {
    int oc = (reg & 3) + 8 * (reg >> 2) + 4 * (lane >> 5);
    if (oc < OCH_) {
      float v = acc[reg] + ob[oc];
      offout[((b * OCH_ + oc) * H_ + ho) * W_ + px] = f2bf(v);
    }
  }
}

__global__ __launch_bounds__(256) void deform_mfma(
    const float* __restrict__ x, const float* __restrict__ bias,
    const unsigned short* __restrict__ w2b, const unsigned short* __restrict__ offb,
    float* __restrict__ out) {
  const int ho = blockIdx.x & (H_ - 1);
  const int b  = blockIdx.x >> 7;
  const int lane = threadIdx.x & 63;
  const int wv   = threadIdx.x >> 6;
  const int px   = wv * 32 + (lane & 31);
  const int cb   = (lane >> 5) * 8;
  const float* xb = x + (size_t)b * C_ * HW_;
  f32x16 acc0, acc1;
  #pragma unroll
  for (int r = 0; r < 16; ++r) { acc0[r] = 0.f; acc1[r] = 0.f; }
  for (int t = 0; t < 9; ++t) {
    const int ki = t / 3, kj = t - 3 * ki;
    float dy = bf2f(offb[((b * OCH_ + 2 * t)     * H_ + ho) * W_ + px]);
    float dx = bf2f(offb[((b * OCH_ + 2 * t + 1) * H_ + ho) * W_ + px]);
    float ys = (float)(ho - 1 + ki) + dy;
    float xs = (float)(px - 1 + kj) + dx;
    float y0f = floorf(ys), x0f = floorf(xs);
    int y0 = (int)y0f, x0 = (int)x0f;
    int y1 = y0 + 1,   x1 = x0 + 1;
    float wy1 = ys - y0f, wx1 = xs - x0f;
    float wy0 = 1.f - wy1, wx0 = 1.f - wx1;
    bool vy0 = (unsigned)y0 < (unsigned)H_, vy1 = (unsigned)y1 < (unsigned)H_;
    bool vx0 = (unsigned)x0 < (unsigned)W_, vx1 = (unsigned)x1 < (unsigned)W_;
    int yc0 = min(max(y0, 0), H_ - 1), yc1 = min(max(y1, 0), H_ - 1);
    int xc0 = min(max(x0, 0), W_ - 1), xc1 = min(max(x1, 0), W_ - 1);
    const int o00 = yc0 * W_ + xc0, o01 = yc0 * W_ + xc1;
    const int o10 = yc1 * W_ + xc0, o11 = yc1 * W_ + xc1;
    const float g00 = (vy0 && vx0) ? wy0 * wx0 : 0.f;
    const float g01 = (vy0 && vx1) ? wy0 * wx1 : 0.f;
    const float g10 = (vy1 && vx0) ? wy1 * wx0 : 0.f;
    const float g11 = (vy1 && vx1) ? wy1 * wx1 : 0.f;
    const short8* wp = (const short8*)(w2b + (size_t)t * 2 * 4 * 64 * 8);
    short8 a0[4], a1[4];
    #pragma unroll
    for (int s = 0; s < 4; ++s) {
      a0[s] = wp[s * 64 + lane];
      a1[s] = wp[(4 + s) * 64 + lane];
    }
    #pragma unroll
    for (int s = 0; s < 4; ++s) {
      const int cidx = (cb + 16 * s) * HW_;
      short8 bf;
      #pragma unroll
      for (int i = 0; i < 8; ++i) {
        const int bi = cidx + i * HW_;
        float v = g00 * xb[bi + o00] + g01 * xb[bi + o01]
                + g10 * xb[bi + o10] + g11 * xb[bi + o11];
        bf[i] = (short)f2bf(v);
      }
      acc0 = __builtin_amdgcn_mfma_f32_32x32x16_bf16(a0[s], bf, acc0, 0, 0, 0);
      acc1 = __builtin_amdgcn_mfma_f32_32x32x16_bf16(a1[s], bf, acc1, 0, 0, 0);
    }
  }
  #pragma unroll
  for (int reg = 0; reg < 16; ++reg) {
    int row = (reg & 3) + 8 * (reg >> 2) + 4 * (lane >> 5);
    out[((b * 64 + row)      * H_ + ho) * W_ + px] = acc0[reg] + bias[row];
    out[((b * 64 + 32 + row) * H_ + ho) * W_ + px] = acc1[reg] + bias[32 + row];
  }
}

extern "C" void kernel_launch(void* const* d_in, const int* in_sizes, int n_in,
                              void* d_out, int out_size, void* d_ws, size_t ws_size,
                              hipStream_t stream) {
  const float* x    = (const float*)d_in[0];
  const float* wt   = (const float*)d_in[1];
  const float* bias = (const float*)d_in[2];
  const float* ow   = (const float*)d_in[3];
  const float* ob   = (const float*)d_in[4];
  float* out = (float*)d_out;

  unsigned short* ws_u  = (unsigned short*)d_ws;
  unsigned short* w2b   = ws_u;
  unsigned short* w2a   = ws_u + W2B_ELEMS;
  unsigned short* offbf = (unsigned short*)((char*)d_ws + OFF_BYTE_OFS);
  unsigned short* xh    = (unsigned short*)((char*)d_ws + XH_BYTE_OFS);

  int pack_total = W2B_ELEMS + W2A_ELEMS;
  pack_w<<<(pack_total + 255) / 256, 256, 0, stream>>>(wt, ow, ws_u);

  if (ws_size >= WS_NEED) {
    nhwc_pack<<<B_ * H_, 256, 0, stream>>>(x, xh);
    offset_conv_nhwc<<<B_ * H_, 256, 0, stream>>>(xh, ob, w2a, offbf);
    deform_nhwc<<<B_ * H_, 256, 0, stream>>>(xh, bias, w2b, offbf, out);
  } else {
    offset_conv_mfma<<<B_ * H_, 256, 0, stream>>>(x, ob, w2a, offbf);
    deform_mfma<<<B_ * H_, 256, 0, stream>>>(x, bias, w2b, offbf, out);
  }
}

// Round 5
// 60.339 us; speedup vs baseline: 7.5523x; 1.1469x over previous
//
#include <hip/hip_runtime.h>
#include <hip/hip_bf16.h>

#define B_ 4
#define C_ 64
#define H_ 128
#define W_ 128
#define HW_ (H_ * W_)
#define OCH_ 18

typedef __attribute__((ext_vector_type(8))) short short8;
typedef __attribute__((ext_vector_type(16))) float f32x16;

// ws layout (bytes):
//   [0, 73728)                      w2b: main weights, A-frag order (bf16)
//   [73728, 110592)                 w2a: offset-conv weights, A-frag order (bf16)
//   [131072, 131072+2359296)        offsets buffer (fallback path only)
//   [2490368, 2490368+8388608)      xh : x in NHWC bf16, [b][h][w][c]
#define W2B_ELEMS (9 * 2 * 4 * 64 * 8)   // 36864
#define W2A_ELEMS (36 * 64 * 8)          // 18432
#define OFF_BYTE_OFS 131072
#define XH_BYTE_OFS  2490368
#define WS_NEED (XH_BYTE_OFS + (size_t)B_ * H_ * W_ * C_ * 2)

__device__ __forceinline__ unsigned short f2bf(float f) {
  union { float f; unsigned u; } v; v.f = f;
  unsigned r = v.u + 0x7FFFu + ((v.u >> 16) & 1u);   // RNE
  return (unsigned short)(r >> 16);
}
__device__ __forceinline__ float bf2f(unsigned short h) {
  union { unsigned u; float f; } v; v.u = ((unsigned)h) << 16;
  return v.f;
}
__device__ __forceinline__ short f2bfh(float f) {     // hot path: HW cvt
  __hip_bfloat16 h = __float2bfloat16(f);
  return *reinterpret_cast<short*>(&h);
}
// bijective XCD swizzle for 512-block grids (512 % 8 == 0)
__device__ __forceinline__ int swz512(int x) { return (x & 7) * 64 + (x >> 3); }

// ---------------- weight pack (shared by both paths) ----------------
__device__ __forceinline__ void pack_weights_body(
    int idx, const float* __restrict__ wmain, const float* __restrict__ offw,
    unsigned short* __restrict__ ws_u) {
  if (idx < W2B_ELEMS) {
    int i = idx & 7, lane = (idx >> 3) & 63, s = (idx >> 9) & 3;
    int mq = (idx >> 11) & 1, t = idx >> 12;
    int o = mq * 32 + (lane & 31);
    int c = 16 * s + (lane >> 5) * 8 + i;
    ws_u[idx] = f2bf(wmain[(o * 64 + c) * 9 + t]);
  } else if (idx < W2B_ELEMS + W2A_ELEMS) {
    int j = idx - W2B_ELEMS;
    int i = j & 7, lane = (j >> 3) & 63, s = j >> 9;   // s 0..35
    int kg = 16 * s + (lane >> 5) * 8 + i;
    int t = kg >> 6, c = kg & 63, oc = lane & 31;
    ws_u[idx] = (oc < OCH_) ? f2bf(offw[(oc * 64 + c) * 9 + t]) : (unsigned short)0;
  }
}

// ---------------- prep kernel: NHWC repack (blocks 0..511) + weight pack (512+) ----------
__global__ __launch_bounds__(256) void prep_kernel(
    const float* __restrict__ x, const float* __restrict__ wmain,
    const float* __restrict__ offw, unsigned short* __restrict__ ws_u,
    unsigned short* __restrict__ xh) {
  const int tid = threadIdx.x;
  if (blockIdx.x < 512) {
    __shared__ float s[W_ * 65];
    const int h = blockIdx.x & (H_ - 1);
    const int b = blockIdx.x >> 7;
    const float* xb = x + ((size_t)b * C_ * H_ + h) * W_;
    for (int i = tid; i < C_ * W_; i += 256) {
      int c = i >> 7, w = i & (W_ - 1);
      s[w * 65 + c] = xb[(size_t)c * HW_ + w];
    }
    __syncthreads();
    unsigned short* dst = xh + ((size_t)(b * H_ + h) * W_) * C_;
    for (int i = tid; i < W_ * 8; i += 256) {
      int w = i >> 3, g = i & 7;
      short8 v;
      #pragma unroll
      for (int j = 0; j < 8; ++j) v[j] = (short)f2bf(s[w * 65 + g * 8 + j]);
      *(short8*)&dst[w * C_ + g * 8] = v;
    }
  } else {
    pack_weights_body((blockIdx.x - 512) * 256 + tid, x ? wmain : wmain, offw, ws_u);
  }
}

__global__ __launch_bounds__(256) void pack_w_only(
    const float* __restrict__ wmain, const float* __restrict__ offw,
    unsigned short* __restrict__ ws_u) {
  pack_weights_body(blockIdx.x * 256 + threadIdx.x, wmain, offw, ws_u);
}

// ---------------- fused kernel: offset conv (phase 1) + deform + einsum (phase 2) --------
// block = (b, ho): 512 blocks x 512 threads (8 waves).
// Wave pair `pair` owns px strip [32*pair, 32*pair+32); sub=wave&1 splits K:
//   phase 1: sub0 -> K-steps 0..17, sub1 -> 18..35     (offset conv, M=32/18 oc)
//   phase 2: sub0 -> taps 0..3,    sub1 -> taps 4..8   (main conv,  M=64)
__global__ __launch_bounds__(512, 4) void deform_fused(
    const unsigned short* __restrict__ xh, const float* __restrict__ bias,
    const float* __restrict__ ob, const unsigned short* __restrict__ w2b,
    const unsigned short* __restrict__ w2a, float* __restrict__ out) {
  const int blk = swz512(blockIdx.x);
  const int ho = blk & (H_ - 1);
  const int b  = blk >> 7;
  const int lane = threadIdx.x & 63;
  const int wave = threadIdx.x >> 6;
  const int pair = wave >> 1;
  const int sub  = wave & 1;
  const int px   = pair * 32 + (lane & 31);
  const int cb   = (lane >> 5) * 8;

  __shared__ float smem[8192];          // 32 KB: red1[16][4][64] | off @4096 | red2[32][4][64]

  // ================= phase 1: offset conv (K-split halves) =================
  f32x16 pacc;
  #pragma unroll
  for (int r = 0; r < 16; ++r) pacc[r] = 0.f;

  const int s0 = sub * 18;
  #pragma unroll 6
  for (int q = 0; q < 18; ++q) {
    const int s  = s0 + q;
    const int t  = s >> 2;
    const int ki = t / 3, kj = t - 3 * ki;
    const int row = ho - 1 + ki;
    const int col = px - 1 + kj;
    short8 bfr = {0, 0, 0, 0, 0, 0, 0, 0};
    if ((unsigned)row < (unsigned)H_ && (unsigned)col < (unsigned)W_)
      bfr = *(const short8*)&xh[(((b * H_ + row) * W_ + col) * C_) + (s & 3) * 16 + cb];
    const short8 afr = *(const short8*)&w2a[(s * 64 + lane) * 8];
    pacc = __builtin_amdgcn_mfma_f32_32x32x16_bf16(afr, bfr, pacc, 0, 0, 0);
  }

  if (sub) {
    #pragma unroll
    for (int i = 0; i < 16; ++i) smem[(i * 4 + pair) * 64 + lane] = pacc[i];
  }
  __syncthreads();
  if (!sub) {
    #pragma unroll
    for (int i = 0; i < 16; ++i) pacc[i] += smem[(i * 4 + pair) * 64 + lane];
    #pragma unroll
    for (int reg = 0; reg < 16; ++reg) {
      int oc = (reg & 3) + 8 * (reg >> 2) + 4 * (lane >> 5);
      if (oc < OCH_)
        smem[4096 + (pair * OCH_ + oc) * 32 + (lane & 31)] = pacc[reg] + ob[oc];
    }
  }
  __syncthreads();

  // read this wave's taps' offsets into registers (static reg indices)
  const int t0 = sub * 4;               // sub0: taps 0..3, sub1: taps 4..8
  const int nt = 4 + sub;
  float dyr[5], dxr[5];
  #pragma unroll
  for (int j = 0; j < 5; ++j) {
    int tt = t0 + ((j < nt) ? j : 0);
    dyr[j] = smem[4096 + (pair * OCH_ + 2 * tt)     * 32 + (lane & 31)];
    dxr[j] = smem[4096 + (pair * OCH_ + 2 * tt + 1) * 32 + (lane & 31)];
  }
  __syncthreads();                      // offsets consumed; smem reusable

  // ================= phase 2: deformable sample + einsum (tap-split) =================
  f32x16 acc0, acc1;
  #pragma unroll
  for (int r = 0; r < 16; ++r) { acc0[r] = 0.f; acc1[r] = 0.f; }

  #pragma unroll
  for (int j = 0; j < 5; ++j) {
    if (j >= nt) continue;              // wave-uniform
    const int t  = t0 + j;
    const int ki = t / 3, kj = t - 3 * ki;
    float ys = (float)(ho - 1 + ki) + dyr[j];
    float xs = (float)(px - 1 + kj) + dxr[j];
    float y0f = floorf(ys), x0f = floorf(xs);
    int y0 = (int)y0f, x0 = (int)x0f;
    int y1 = y0 + 1,   x1 = x0 + 1;
    float wy1 = ys - y0f, wx1 = xs - x0f;
    float wy0 = 1.f - wy1, wx0 = 1.f - wx1;
    bool vy0 = (unsigned)y0 < (unsigned)H_, vy1 = (unsigned)y1 < (unsigned)H_;
    bool vx0 = (unsigned)x0 < (unsigned)W_, vx1 = (unsigned)x1 < (unsigned)W_;
    int yc0 = min(max(y0, 0), H_ - 1), yc1 = min(max(y1, 0), H_ - 1);
    int xc0 = min(max(x0, 0), W_ - 1), xc1 = min(max(x1, 0), W_ - 1);
    const float g00 = (vy0 && vx0) ? wy0 * wx0 : 0.f;
    const float g01 = (vy0 && vx1) ? wy0 * wx1 : 0.f;
    const float g10 = (vy1 && vx0) ? wy1 * wx0 : 0.f;
    const float g11 = (vy1 && vx1) ? wy1 * wx1 : 0.f;
    const int p00 = ((b * H_ + yc0) * W_ + xc0) * C_ + cb;
    const int p01 = ((b * H_ + yc0) * W_ + xc1) * C_ + cb;
    const int p10 = ((b * H_ + yc1) * W_ + xc0) * C_ + cb;
    const int p11 = ((b * H_ + yc1) * W_ + xc1) * C_ + cb;
    const short8* wp = (const short8*)(w2b + (size_t)t * 2 * 4 * 64 * 8);

    #pragma unroll
    for (int half = 0; half < 2; ++half) {        // cap corner-reg pressure
      short8 cr[2][4];
      #pragma unroll
      for (int s = 0; s < 2; ++s) {
        const int ss = half * 2 + s;
        cr[s][0] = *(const short8*)&xh[p00 + 16 * ss];
        cr[s][1] = *(const short8*)&xh[p01 + 16 * ss];
        cr[s][2] = *(const short8*)&xh[p10 + 16 * ss];
        cr[s][3] = *(const short8*)&xh[p11 + 16 * ss];
      }
      short8 a0h[2], a1h[2];
      #pragma unroll
      for (int s = 0; s < 2; ++s) {
        a0h[s] = wp[(half * 2 + s) * 64 + lane];
        a1h[s] = wp[(4 + half * 2 + s) * 64 + lane];
      }
      #pragma unroll
      for (int s = 0; s < 2; ++s) {
        short8 bf;
        #pragma unroll
        for (int i = 0; i < 8; ++i) {
          float v = g00 * bf2f((unsigned short)cr[s][0][i])
                  + g01 * bf2f((unsigned short)cr[s][1][i])
                  + g10 * bf2f((unsigned short)cr[s][2][i])
                  + g11 * bf2f((unsigned short)cr[s][3][i]);
          bf[i] = f2bfh(v);
        }
        acc0 = __builtin_amdgcn_mfma_f32_32x32x16_bf16(a0h[s], bf, acc0, 0, 0, 0);
        acc1 = __builtin_amdgcn_mfma_f32_32x32x16_bf16(a1h[s], bf, acc1, 0, 0, 0);
      }
    }
  }

  // ---- pairwise reduction + epilogue ----
  if (sub) {
    #pragma unroll
    for (int i = 0; i < 16; ++i) {
      smem[(i * 4 + pair) * 64 + lane]        = acc0[i];
      smem[((16 + i) * 4 + pair) * 64 + lane] = acc1[i];
    }
  }
  __syncthreads();
  if (!sub) {
    #pragma unroll
    for (int i = 0; i < 16; ++i) {
      acc0[i] += smem[(i * 4 + pair) * 64 + lane];
      acc1[i] += smem[((16 + i) * 4 + pair) * 64 + lane];
    }
    #pragma unroll
    for (int reg = 0; reg < 16; ++reg) {
      int row = (reg & 3) + 8 * (reg >> 2) + 4 * (lane >> 5);
      out[((b * 64 + row)      * H_ + ho) * W_ + px] = acc0[reg] + bias[row];
      out[((b * 64 + 32 + row) * H_ + ho) * W_ + px] = acc1[reg] + bias[32 + row];
    }
  }
}

// ================= fallback path (round-3 CHW, used only if ws too small) =================
__global__ __launch_bounds__(256) void offset_conv_mfma(
    const float* __restrict__ x, const float* __restrict__ ob,
    const unsigned short* __restrict__ w2a, unsigned short* __restrict__ offout) {
  const int ho = blockIdx.x & (H_ - 1);
  const int b  = blockIdx.x >> 7;
  const int tid = threadIdx.x;
  const int lane = tid & 63;
  const int wv = tid >> 6;
  __shared__ __align__(16) unsigned short sx[3 * 130 * 64];
  const float* xb = x + (size_t)b * C_ * HW_;
  for (int i = tid; i < 96 * 130; i += 256) {
    int col = i % 130;
    int c2  = i / 130;
    int r   = c2 >> 5;
    int c   = (c2 & 31) * 2;
    int row = ho - 1 + r, gcol = col - 1;
    float v0 = 0.f, v1 = 0.f;
    if ((unsigned)row < (unsigned)H_ && (unsigned)gcol < (unsigned)W_) {
      v0 = xb[(size_t)c * HW_ + row * W_ + gcol];
      v1 = xb[(size_t)(c + 1) * HW_ + row * W_ + gcol];
    }
    unsigned pk = (unsigned)f2bf(v0) | ((unsigned)f2bf(v1) << 16);
    int cblk = (c >> 3) ^ (col & 7);
    int h = ((r * 130 + col) * 8 + cblk) * 8 + (c & 7);
    *(unsigned*)&sx[h] = pk;
  }
  __syncthreads();
  const int px  = wv * 32 + (lane & 31);
  const int cbh = lane >> 5;
  f32x16 acc;
  #pragma unroll
  for (int r = 0; r < 16; ++r) acc[r] = 0.f;
  for (int s = 0; s < 36; ++s) {
    int t  = s >> 2;
    int ki = t / 3, kj = t - 3 * ki;
    int j  = px + kj;
    int cblk = (s & 3) * 2 + cbh;
    const short8 bfr = *(const short8*)&sx[((ki * 130 + j) * 8 + (cblk ^ (j & 7))) * 8];
    const short8 afr = *(const short8*)&w2a[(s * 64 + lane) * 8];
    acc = __builtin_amdgcn_mfma_f32_32x32x16_bf16(afr, bfr, acc, 0, 0, 0);
  }
  #pragma unroll
  for (int reg = 0; reg < 16; ++reg) {
    int oc = (reg & 3) + 8 * (reg >> 2) + 4 * (lane >> 5);
    if (oc < OCH_) {
      float v = acc[reg] + ob[oc];
      offout[((b * OCH_ + oc) * H_ + ho) * W_ + px] = f2bf(v);
    }
  }
}

__global__ __launch_bounds__(256) void deform_mfma(
    const float* __restrict__ x, const float* __restrict__ bias,
    const unsigned short* __restrict__ w2b, const unsigned short* __restrict__ offb,
    float* __restrict__ out) {
  const int ho = blockIdx.x & (H_ - 1);
  const int b  = blockIdx.x >> 7;
  const int lane = threadIdx.x & 63;
  const int wv   = threadIdx.x >> 6;
  const int px   = wv * 32 + (lane & 31);
  const int cb   = (lane >> 5) * 8;
  const float* xb = x + (size_t)b * C_ * HW_;
  f32x16 acc0, acc1;
  #pragma unroll
  for (int r = 0; r < 16; ++r) { acc0[r] = 0.f; acc1[r] = 0.f; }
  for (int t = 0; t < 9; ++t) {
    const int ki = t / 3, kj = t - 3 * ki;
    float dy = bf2f(offb[((b * OCH_ + 2 * t)     * H_ + ho) * W_ + px]);
    float dx = bf2f(offb[((b * OCH_ + 2 * t + 1) * H_ + ho) * W_ + px]);
    float ys = (float)(ho - 1 + ki) + dy;
    float xs = (float)(px - 1 + kj) + dx;
    float y0f = floorf(ys), x0f = floorf(xs);
    int y0 = (int)y0f, x0 = (int)x0f;
    int y1 = y0 + 1,   x1 = x0 + 1;
    float wy1 = ys - y0f, wx1 = xs - x0f;
    float wy0 = 1.f - wy1, wx0 = 1.f - wx1;
    bool vy0 = (unsigned)y0 < (unsigned)H_, vy1 = (unsigned)y1 < (unsigned)H_;
    bool vx0 = (unsigned)x0 < (unsigned)W_, vx1 = (unsigned)x1 < (unsigned)W_;
    int yc0 = min(max(y0, 0), H_ - 1), yc1 = min(max(y1, 0), H_ - 1);
    int xc0 = min(max(x0, 0), W_ - 1), xc1 = min(max(x1, 0), W_ - 1);
    const int o00 = yc0 * W_ + xc0, o01 = yc0 * W_ + xc1;
    const int o10 = yc1 * W_ + xc0, o11 = yc1 * W_ + xc1;
    const float g00 = (vy0 && vx0) ? wy0 * wx0 : 0.f;
    const float g01 = (vy0 && vx1) ? wy0 * wx1 : 0.f;
    const float g10 = (vy1 && vx0) ? wy1 * wx0 : 0.f;
    const float g11 = (vy1 && vx1) ? wy1 * wx1 : 0.f;
    const short8* wp = (const short8*)(w2b + (size_t)t * 2 * 4 * 64 * 8);
    short8 a0[4], a1[4];
    #pragma unroll
    for (int s = 0; s < 4; ++s) {
      a0[s] = wp[s * 64 + lane];
      a1[s] = wp[(4 + s) * 64 + lane];
    }
    #pragma unroll
    for (int s = 0; s < 4; ++s) {
      const int cidx = (cb + 16 * s) * HW_;
      short8 bf;
      #pragma unroll
      for (int i = 0; i < 8; ++i) {
        const int bi = cidx + i * HW_;
        float v = g00 * xb[bi + o00] + g01 * xb[bi + o01]
                + g10 * xb[bi + o10] + g11 * xb[bi + o11];
        bf[i] = (short)f2bf(v);
      }
      acc0 = __builtin_amdgcn_mfma_f32_32x32x16_bf16(a0[s], bf, acc0, 0, 0, 0);
      acc1 = __builtin_amdgcn_mfma_f32_32x32x16_bf16(a1[s], bf, acc1, 0, 0, 0);
    }
  }
  #pragma unroll
  for (int reg = 0; reg < 16; ++reg) {
    int row = (reg & 3) + 8 * (reg >> 2) + 4 * (lane >> 5);
    out[((b * 64 + row)      * H_ + ho) * W_ + px] = acc0[reg] + bias[row];
    out[((b * 64 + 32 + row) * H_ + ho) * W_ + px] = acc1[reg] + bias[32 + row];
  }
}

extern "C" void kernel_launch(void* const* d_in, const int* in_sizes, int n_in,
                              void* d_out, int out_size, void* d_ws, size_t ws_size,
                              hipStream_t stream) {
  const float* x    = (const float*)d_in[0];
  const float* wt   = (const float*)d_in[1];
  const float* bias = (const float*)d_in[2];
  const float* ow   = (const float*)d_in[3];
  const float* ob   = (const float*)d_in[4];
  float* out = (float*)d_out;

  unsigned short* ws_u  = (unsigned short*)d_ws;
  unsigned short* w2b   = ws_u;
  unsigned short* w2a   = ws_u + W2B_ELEMS;
  unsigned short* offbf = (unsigned short*)((char*)d_ws + OFF_BYTE_OFS);
  unsigned short* xh    = (unsigned short*)((char*)d_ws + XH_BYTE_OFS);

  const int pack_blocks = (W2B_ELEMS + W2A_ELEMS + 255) / 256;   // 216

  if (ws_size >= WS_NEED) {
    prep_kernel<<<512 + pack_blocks, 256, 0, stream>>>(x, wt, ow, ws_u, xh);
    deform_fused<<<512, 512, 0, stream>>>(xh, bias, ob, w2b, w2a, out);
  } else {
    pack_w_only<<<pack_blocks, 256, 0, stream>>>(wt, ow, ws_u);
    offset_conv_mfma<<<B_ * H_, 256, 0, stream>>>(x, ob, w2a, offbf);
    deform_mfma<<<B_ * H_, 256, 0, stream>>>(x, bias, w2b, offbf, out);
  }
}

// Round 6
// 43.050 us; speedup vs baseline: 10.5855x; 1.4016x over previous
//
#include <hip/hip_runtime.h>
#include <hip/hip_bf16.h>

#define B_ 4
#define C_ 64
#define H_ 128
#define W_ 128
#define HW_ (H_ * W_)
#define OCH_ 18

typedef __attribute__((ext_vector_type(8))) short short8;
typedef __attribute__((ext_vector_type(16))) float f32x16;

// ws layout (bytes):
//   [0, 73728)                      w2b: main weights, A-frag order (bf16)
//   [73728, 110592)                 w2a: offset-conv weights, A-frag order (bf16)
//   [131072, 131072+2359296)        offsets buffer (fallback path only)
//   [2490368, 2490368+8388608)      xh : x in NHWC bf16, [b][h][w][c]
#define W2B_ELEMS (9 * 2 * 4 * 64 * 8)   // 36864
#define W2A_ELEMS (36 * 64 * 8)          // 18432
#define OFF_BYTE_OFS 131072
#define XH_BYTE_OFS  2490368
#define WS_NEED (XH_BYTE_OFS + (size_t)B_ * H_ * W_ * C_ * 2)

// LDS window: 4 chunk-planes (8ch each) x 5 rows x 128 cols x 16B, padded plane stride
#define PSTRIDE_B 10256                  // 5*128*16 + 16 pad (stride % 128B != 0)
#define WIN_BYTES (4 * PSTRIDE_B)        // 41024

__device__ __forceinline__ unsigned short f2bf(float f) {
  union { float f; unsigned u; } v; v.f = f;
  unsigned r = v.u + 0x7FFFu + ((v.u >> 16) & 1u);   // RNE
  return (unsigned short)(r >> 16);
}
__device__ __forceinline__ float bf2f(unsigned short h) {
  union { unsigned u; float f; } v; v.u = ((unsigned)h) << 16;
  return v.f;
}
__device__ __forceinline__ short f2bfh(float f) {     // hot path: HW cvt
  __hip_bfloat16 h = __float2bfloat16(f);
  return *reinterpret_cast<short*>(&h);
}
// bijective XCD swizzle for 512-block grids (512 % 8 == 0)
__device__ __forceinline__ int swz512(int x) { return (x & 7) * 64 + (x >> 3); }

// ---------------- weight pack (shared by both paths) ----------------
__device__ __forceinline__ void pack_weights_body(
    int idx, const float* __restrict__ wmain, const float* __restrict__ offw,
    unsigned short* __restrict__ ws_u) {
  if (idx < W2B_ELEMS) {
    int i = idx & 7, lane = (idx >> 3) & 63, s = (idx >> 9) & 3;
    int mq = (idx >> 11) & 1, t = idx >> 12;
    int o = mq * 32 + (lane & 31);
    int c = 16 * s + (lane >> 5) * 8 + i;
    ws_u[idx] = f2bf(wmain[(o * 64 + c) * 9 + t]);
  } else if (idx < W2B_ELEMS + W2A_ELEMS) {
    int j = idx - W2B_ELEMS;
    int i = j & 7, lane = (j >> 3) & 63, s = j >> 9;   // s 0..35
    int kg = 16 * s + (lane >> 5) * 8 + i;
    int t = kg >> 6, c = kg & 63, oc = lane & 31;
    ws_u[idx] = (oc < OCH_) ? f2bf(offw[(oc * 64 + c) * 9 + t]) : (unsigned short)0;
  }
}

// ---------------- prep kernel: NHWC repack (blocks 0..511) + weight pack (512+) ----------
__global__ __launch_bounds__(256) void prep_kernel(
    const float* __restrict__ x, const float* __restrict__ wmain,
    const float* __restrict__ offw, unsigned short* __restrict__ ws_u,
    unsigned short* __restrict__ xh) {
  const int tid = threadIdx.x;
  if (blockIdx.x < 512) {
    __shared__ float s[W_ * 65];
    const int h = blockIdx.x & (H_ - 1);
    const int b = blockIdx.x >> 7;
    const float* xb = x + ((size_t)b * C_ * H_ + h) * W_;
    for (int i = tid; i < C_ * W_; i += 256) {
      int c = i >> 7, w = i & (W_ - 1);
      s[w * 65 + c] = xb[(size_t)c * HW_ + w];
    }
    __syncthreads();
    unsigned short* dst = xh + ((size_t)(b * H_ + h) * W_) * C_;
    for (int i = tid; i < W_ * 8; i += 256) {
      int w = i >> 3, g = i & 7;
      short8 v;
      #pragma unroll
      for (int j = 0; j < 8; ++j) v[j] = (short)f2bf(s[w * 65 + g * 8 + j]);
      *(short8*)&dst[w * C_ + g * 8] = v;
    }
  } else {
    pack_weights_body((blockIdx.x - 512) * 256 + tid, wmain, offw, ws_u);
  }
}

__global__ __launch_bounds__(256) void pack_w_only(
    const float* __restrict__ wmain, const float* __restrict__ offw,
    unsigned short* __restrict__ ws_u) {
  pack_weights_body(blockIdx.x * 256 + threadIdx.x, wmain, offw, ws_u);
}

// ---------------- per-tap deform+MFMA body (window gather, rare global fallback) ---------
template<int KI, int KJ, int CPH>
__device__ __forceinline__ void tap_body(
    float dy, float dx, int ho, int px, int lane, int b,
    const char* __restrict__ win, const unsigned short* __restrict__ xh,
    const unsigned short* __restrict__ wt2,   // w2b + tap*4096
    f32x16& acc0, f32x16& acc1) {
  const float ys = (float)(ho - 1 + KI) + dy;
  const float xs = (float)(px - 1 + KJ) + dx;
  const float y0f = floorf(ys), x0f = floorf(xs);
  const int y0 = (int)y0f, x0 = (int)x0f;
  const int y1 = y0 + 1, x1 = x0 + 1;
  const float wy1 = ys - y0f, wx1 = xs - x0f;
  const float wy0 = 1.f - wy1, wx0 = 1.f - wx1;
  const bool vy0 = (unsigned)y0 < (unsigned)H_, vy1 = (unsigned)y1 < (unsigned)H_;
  const bool vx0 = (unsigned)x0 < (unsigned)W_, vx1 = (unsigned)x1 < (unsigned)W_;
  const float g00 = (vy0 && vx0) ? wy0 * wx0 : 0.f;
  const float g01 = (vy0 && vx1) ? wy0 * wx1 : 0.f;
  const float g10 = (vy1 && vx0) ? wy1 * wx0 : 0.f;
  const float g11 = (vy1 && vx1) ? wy1 * wx1 : 0.f;
  const int yc0 = min(max(y0, 0), H_ - 1), yc1 = min(max(y1, 0), H_ - 1);
  const int xc0 = min(max(x0, 0), W_ - 1), xc1 = min(max(x1, 0), W_ - 1);
  const int rr0 = yc0 - ho + 2, rr1 = yc1 - ho + 2;
  const bool in0 = (unsigned)rr0 < 5u, in1 = (unsigned)rr1 < 5u;
  const int r0 = min(max(rr0, 0), 4), r1 = min(max(rr1, 0), 4);
  const int u00 = (r0 * 128 + xc0) << 4, u01 = (r0 * 128 + xc1) << 4;
  const int u10 = (r1 * 128 + xc0) << 4, u11 = (r1 * 128 + xc1) << 4;
  const int laneh = lane >> 5;
  #pragma unroll
  for (int ssl = 0; ssl < 2; ++ssl) {
    const int ss = CPH * 2 + ssl;
    const char* pb = win + (2 * ssl + laneh) * PSTRIDE_B;
    short8 c00 = *(const short8*)(pb + u00);
    short8 c01 = *(const short8*)(pb + u01);
    short8 c10 = *(const short8*)(pb + u10);
    short8 c11 = *(const short8*)(pb + u11);
    if (!in0 || !in1) {                         // rare (|dy| >= ~1)
      const int ch8 = (2 * ss + laneh) << 3;
      if (!in0) {
        c00 = *(const short8*)&xh[(((size_t)((b * H_ + yc0) * W_ + xc0)) << 6) + ch8];
        c01 = *(const short8*)&xh[(((size_t)((b * H_ + yc0) * W_ + xc1)) << 6) + ch8];
      }
      if (!in1) {
        c10 = *(const short8*)&xh[(((size_t)((b * H_ + yc1) * W_ + xc0)) << 6) + ch8];
        c11 = *(const short8*)&xh[(((size_t)((b * H_ + yc1) * W_ + xc1)) << 6) + ch8];
      }
    }
    short8 bf;
    #pragma unroll
    for (int i = 0; i < 8; ++i) {
      float v = g00 * bf2f((unsigned short)c00[i]) + g01 * bf2f((unsigned short)c01[i])
              + g10 * bf2f((unsigned short)c10[i]) + g11 * bf2f((unsigned short)c11[i]);
      bf[i] = f2bfh(v);
    }
    const short8 a0 = *(const short8*)&wt2[(ss * 64 + lane) * 8];
    const short8 a1 = *(const short8*)&wt2[((4 + ss) * 64 + lane) * 8];
    acc0 = __builtin_amdgcn_mfma_f32_32x32x16_bf16(a0, bf, acc0, 0, 0, 0);
    acc1 = __builtin_amdgcn_mfma_f32_32x32x16_bf16(a1, bf, acc1, 0, 0, 0);
  }
}

// stage 4 chunk-planes (channels 32*CPH..+31) of rows ho-2..ho+2 (clamped) into LDS
#define STAGEW(CPH)                                                                     \
  _Pragma("unroll")                                                                     \
  for (int it = 0; it < 5; ++it) {                                                      \
    const int i = tid + it * 512;                                                       \
    const int p = i & 3;                                                                \
    const int xcol = (i >> 2) & 127;                                                    \
    const int r = i >> 9;                                                               \
    const int srow = min(H_ - 1, max(0, ho - 2 + r));                                   \
    const short8 v = *(const short8*)&xh[(((size_t)((b * H_ + srow) * W_ + xcol)) << 6) \
                                         + ((4 * (CPH) + p) << 3)];                     \
    *(short8*)(smem + p * PSTRIDE_B + ((r * 128 + xcol) << 4)) = v;                     \
  }

// offset-conv half: 18 K-steps with (s&3) in {2*CPH, 2*CPH+1}, read from window
#define P1HALF(CPH)                                                                     \
  _Pragma("unroll")                                                                     \
  for (int t = 0; t < 9; ++t) {                                                         \
    _Pragma("unroll")                                                                   \
    for (int q = 0; q < 2; ++q) {                                                       \
      const int s = 4 * t + 2 * (CPH) + q;                                              \
      const int ki = t / 3, kj = t - 3 * (t / 3);                                       \
      const int row = ho - 1 + ki, col = px - 1 + kj;                                   \
      short8 bfr = {0, 0, 0, 0, 0, 0, 0, 0};                                            \
      if (((unsigned)row < (unsigned)H_) && ((unsigned)col < (unsigned)W_))             \
        bfr = *(const short8*)(smem + (2 * q + laneh) * PSTRIDE_B                       \
                               + (((ki + 1) * 128 + col) << 4));                        \
      const short8 afr = *(const short8*)&w2a[((size_t)s * 64 + lane) * 8];             \
      pacc = __builtin_amdgcn_mfma_f32_32x32x16_bf16(afr, bfr, pacc, 0, 0, 0);          \
    }                                                                                   \
  }

// extract dy/dx for tap T from pacc (C/D layout: row=oc=(reg&3)+8*(reg>>2)+4h, col=px)
#define EXT(T, J)                                                                       \
  {                                                                                     \
    constexpr int ocy = 2 * (T), ocx = 2 * (T) + 1;                                     \
    constexpr int ry = (ocy & 3) + 4 * (ocy >> 3), hy = (ocy >> 2) & 1;                 \
    constexpr int rx = (ocx & 3) + 4 * (ocx >> 3), hx = (ocx >> 2) & 1;                 \
    dys[J] = __shfl(pacc[ry], (lane & 31) + (hy << 5)) + ob[ocy];                       \
    dxs[J] = __shfl(pacc[rx], (lane & 31) + (hx << 5)) + ob[ocx];                       \
  }

#define TAP(KI, KJ, CPH, J)                                                             \
  tap_body<KI, KJ, CPH>(dys[J], dxs[J], ho, px, lane, b, smem, xh,                      \
                        w2b + ((KI) * 3 + (KJ)) * 4096, acc0, acc1)

#define P2CPH(CPH)                                                                      \
  if (sub == 0) {                                                                       \
    TAP(0, 0, CPH, 0); TAP(0, 1, CPH, 1); TAP(0, 2, CPH, 2); TAP(1, 0, CPH, 3);         \
  } else {                                                                              \
    TAP(1, 1, CPH, 0); TAP(1, 2, CPH, 1); TAP(2, 0, CPH, 2); TAP(2, 1, CPH, 3);         \
    TAP(2, 2, CPH, 4);                                                                  \
  }

// ---------------- fused kernel v2: LDS-window gathers ----------------
// block=(b,ho): 512 blocks x 512 threads (8 waves = 4 pairs x 2 subs).
// phase 1: offset conv from window (both subs duplicate -> no reduction, offsets via shfl)
// phase 2: tap-split (sub0: taps 0-3, sub1: 4-8), window gathers, 2 channel-phases
__global__ __launch_bounds__(512, 4) void deform_fused2(
    const unsigned short* __restrict__ xh, const float* __restrict__ bias,
    const float* __restrict__ ob, const unsigned short* __restrict__ w2b,
    const unsigned short* __restrict__ w2a, float* __restrict__ out) {
  const int blk = swz512(blockIdx.x);
  const int ho = blk & (H_ - 1);
  const int b  = blk >> 7;
  const int tid = threadIdx.x;
  const int lane = tid & 63;
  const int wave = tid >> 6;
  const int pair = wave >> 1;
  const int sub  = wave & 1;
  const int px   = pair * 32 + (lane & 31);
  const int laneh = lane >> 5;

  __shared__ __align__(16) char smem[WIN_BYTES];   // 41 KB window; reused for reduction

  // ================= phase 1: offset conv =================
  f32x16 pacc;
  #pragma unroll
  for (int r = 0; r < 16; ++r) pacc[r] = 0.f;

  STAGEW(0);
  __syncthreads();
  P1HALF(0);
  __syncthreads();
  STAGEW(1);
  __syncthreads();
  P1HALF(1);

  // offsets for this wave's taps, wave-internal via shfl
  float dys[5], dxs[5];
  if (sub == 0) {
    EXT(0, 0); EXT(1, 1); EXT(2, 2); EXT(3, 3);
    dys[4] = 0.f; dxs[4] = 0.f;
  } else {
    EXT(4, 0); EXT(5, 1); EXT(6, 2); EXT(7, 3); EXT(8, 4);
  }

  // ================= phase 2: deformable sample + einsum =================
  f32x16 acc0, acc1;
  #pragma unroll
  for (int r = 0; r < 16; ++r) { acc0[r] = 0.f; acc1[r] = 0.f; }

  P2CPH(1);                 // window currently holds channels 32..63
  __syncthreads();
  STAGEW(0);
  __syncthreads();
  P2CPH(0);                 // channels 0..31
  __syncthreads();

  // ---- pairwise (sub) reduction in reused window LDS + epilogue ----
  float* red = (float*)smem;
  if (sub) {
    #pragma unroll
    for (int i = 0; i < 16; ++i) {
      red[(i * 4 + pair) * 64 + lane]        = acc0[i];
      red[((16 + i) * 4 + pair) * 64 + lane] = acc1[i];
    }
  }
  __syncthreads();
  if (!sub) {
    #pragma unroll
    for (int i = 0; i < 16; ++i) {
      acc0[i] += red[(i * 4 + pair) * 64 + lane];
      acc1[i] += red[((16 + i) * 4 + pair) * 64 + lane];
    }
    #pragma unroll
    for (int reg = 0; reg < 16; ++reg) {
      int row = (reg & 3) + 8 * (reg >> 2) + 4 * laneh;
      out[((b * 64 + row)      * H_ + ho) * W_ + px] = acc0[reg] + bias[row];
      out[((b * 64 + 32 + row) * H_ + ho) * W_ + px] = acc1[reg] + bias[32 + row];
    }
  }
}

// ================= fallback path (round-3 CHW, used only if ws too small) =================
__global__ __launch_bounds__(256) void offset_conv_mfma(
    const float* __restrict__ x, const float* __restrict__ ob,
    const unsigned short* __restrict__ w2a, unsigned short* __restrict__ offout) {
  const int ho = blockIdx.x & (H_ - 1);
  const int b  = blockIdx.x >> 7;
  const int tid = threadIdx.x;
  const int lane = tid & 63;
  const int wv = tid >> 6;
  __shared__ __align__(16) unsigned short sx[3 * 130 * 64];
  const float* xb = x + (size_t)b * C_ * HW_;
  for (int i = tid; i < 96 * 130; i += 256) {
    int col = i % 130;
    int c2  = i / 130;
    int r   = c2 >> 5;
    int c   = (c2 & 31) * 2;
    int row = ho - 1 + r, gcol = col - 1;
    float v0 = 0.f, v1 = 0.f;
    if ((unsigned)row < (unsigned)H_ && (unsigned)gcol < (unsigned)W_) {
      v0 = xb[(size_t)c * HW_ + row * W_ + gcol];
      v1 = xb[(size_t)(c + 1) * HW_ + row * W_ + gcol];
    }
    unsigned pk = (unsigned)f2bf(v0) | ((unsigned)f2bf(v1) << 16);
    int cblk = (c >> 3) ^ (col & 7);
    int h = ((r * 130 + col) * 8 + cblk) * 8 + (c & 7);
    *(unsigned*)&sx[h] = pk;
  }
  __syncthreads();
  const int px  = wv * 32 + (lane & 31);
  const int cbh = lane >> 5;
  f32x16 acc;
  #pragma unroll
  for (int r = 0; r < 16; ++r) acc[r] = 0.f;
  for (int s = 0; s < 36; ++s) {
    int t  = s >> 2;
    int ki = t / 3, kj = t - 3 * ki;
    int j  = px + kj;
    int cblk = (s & 3) * 2 + cbh;
    const short8 bfr = *(const short8*)&sx[((ki * 130 + j) * 8 + (cblk ^ (j & 7))) * 8];
    const short8 afr = *(const short8*)&w2a[(s * 64 + lane) * 8];
    acc = __builtin_amdgcn_mfma_f32_32x32x16_bf16(afr, bfr, acc, 0, 0, 0);
  }
  #pragma unroll
  for (int reg = 0; reg < 16; ++reg) {
    int oc = (reg & 3) + 8 * (reg >> 2) + 4 * (lane >> 5);
    if (oc < OCH_) {
      float v = acc[reg] + ob[oc];
      offout[((b * OCH_ + oc) * H_ + ho) * W_ + px] = f2bf(v);
    }
  }
}

__global__ __launch_bounds__(256) void deform_mfma(
    const float* __restrict__ x, const float* __restrict__ bias,
    const unsigned short* __restrict__ w2b, const unsigned short* __restrict__ offb,
    float* __restrict__ out) {
  const int ho = blockIdx.x & (H_ - 1);
  const int b  = blockIdx.x >> 7;
  const int lane = threadIdx.x & 63;
  const int wv   = threadIdx.x >> 6;
  const int px   = wv * 32 + (lane & 31);
  const int cb   = (lane >> 5) * 8;
  const float* xb = x + (size_t)b * C_ * HW_;
  f32x16 acc0, acc1;
  #pragma unroll
  for (int r = 0; r < 16; ++r) { acc0[r] = 0.f; acc1[r] = 0.f; }
  for (int t = 0; t < 9; ++t) {
    const int ki = t / 3, kj = t - 3 * ki;
    float dy = bf2f(offb[((b * OCH_ + 2 * t)     * H_ + ho) * W_ + px]);
    float dx = bf2f(offb[((b * OCH_ + 2 * t + 1) * H_ + ho) * W_ + px]);
    float ys = (float)(ho - 1 + ki) + dy;
    float xs = (float)(px - 1 + kj) + dx;
    float y0f = floorf(ys), x0f = floorf(xs);
    int y0 = (int)y0f, x0 = (int)x0f;
    int y1 = y0 + 1,   x1 = x0 + 1;
    float wy1 = ys - y0f, wx1 = xs - x0f;
    float wy0 = 1.f - wy1, wx0 = 1.f - wx1;
    bool vy0 = (unsigned)y0 < (unsigned)H_, vy1 = (unsigned)y1 < (unsigned)H_;
    bool vx0 = (unsigned)x0 < (unsigned)W_, vx1 = (unsigned)x1 < (unsigned)W_;
    int yc0 = min(max(y0, 0), H_ - 1), yc1 = min(max(y1, 0), H_ - 1);
    int xc0 = min(max(x0, 0), W_ - 1), xc1 = min(max(x1, 0), W_ - 1);
    const int o00 = yc0 * W_ + xc0, o01 = yc0 * W_ + xc1;
    const int o10 = yc1 * W_ + xc0, o11 = yc1 * W_ + xc1;
    const float g00 = (vy0 && vx0) ? wy0 * wx0 : 0.f;
    const float g01 = (vy0 && vx1) ? wy0 * wx1 : 0.f;
    const float g10 = (vy1 && vx0) ? wy1 * wx0 : 0.f;
    const float g11 = (vy1 && vx1) ? wy1 * wx1 : 0.f;
    const short8* wp = (const short8*)(w2b + (size_t)t * 2 * 4 * 64 * 8);
    short8 a0[4], a1[4];
    #pragma unroll
    for (int s = 0; s < 4; ++s) {
      a0[s] = wp[s * 64 + lane];
      a1[s] = wp[(4 + s) * 64 + lane];
    }
    #pragma unroll
    for (int s = 0; s < 4; ++s) {
      const int cidx = (cb + 16 * s) * HW_;
      short8 bf;
      #pragma unroll
      for (int i = 0; i < 8; ++i) {
        const int bi = cidx + i * HW_;
        float v = g00 * xb[bi + o00] + g01 * xb[bi + o01]
                + g10 * xb[bi + o10] + g11 * xb[bi + o11];
        bf[i] = (short)f2bf(v);
      }
      acc0 = __builtin_amdgcn_mfma_f32_32x32x16_bf16(a0[s], bf, acc0, 0, 0, 0);
      acc1 = __builtin_amdgcn_mfma_f32_32x32x16_bf16(a1[s], bf, acc1, 0, 0, 0);
    }
  }
  #pragma unroll
  for (int reg = 0; reg < 16; ++reg) {
    int row = (reg & 3) + 8 * (reg >> 2) + 4 * (lane >> 5);
    out[((b * 64 + row)      * H_ + ho) * W_ + px] = acc0[reg] + bias[row];
    out[((b * 64 + 32 + row) * H_ + ho) * W_ + px] = acc1[reg] + bias[32 + row];
  }
}

extern "C" void kernel_launch(void* const* d_in, const int* in_sizes, int n_in,
                              void* d_out, int out_size, void* d_ws, size_t ws_size,
                              hipStream_t stream) {
  const float* x    = (const float*)d_in[0];
  const float* wt   = (const float*)d_in[1];
  const float* bias = (const float*)d_in[2];
  const float* ow   = (const float*)d_in[3];
  const float* ob   = (const float*)d_in[4];
  float* out = (float*)d_out;

  unsigned short* ws_u  = (unsigned short*)d_ws;
  unsigned short* w2b   = ws_u;
  unsigned short* w2a   = ws_u + W2B_ELEMS;
  unsigned short* offbf = (unsigned short*)((char*)d_ws + OFF_BYTE_OFS);
  unsigned short* xh    = (unsigned short*)((char*)d_ws + XH_BYTE_OFS);

  const int pack_blocks = (W2B_ELEMS + W2A_ELEMS + 255) / 256;   // 216

  if (ws_size >= WS_NEED) {
    prep_kernel<<<512 + pack_blocks, 256, 0, stream>>>(x, wt, ow, ws_u, xh);
    deform_fused2<<<512, 512, 0, stream>>>(xh, bias, ob, w2b, w2a, out);
  } else {
    pack_w_only<<<pack_blocks, 256, 0, stream>>>(wt, ow, ws_u);
    offset_conv_mfma<<<B_ * H_, 256, 0, stream>>>(x, ob, w2a, offbf);
    deform_mfma<<<B_ * H_, 256, 0, stream>>>(x, bias, w2b, offbf, out);
  }
}